// Round 14
// baseline (274.765 us; speedup 1.0000x reference)
//
#include <hip/hip_runtime.h>
#include <stdint.h>

#define BATCH 32
#define CH    256
#define TLEN  4096
#define TN    64
#define TPAD  4100          // aT rows per batch strip: 2 pad + 4096 + 2 pad
#define SST   68            // phase-B f32 scratch row stride

typedef short    bf16x8 __attribute__((ext_vector_type(8)));
typedef float    f32x4  __attribute__((ext_vector_type(4)));
typedef uint16_t u16x4  __attribute__((ext_vector_type(4)));
typedef uint16_t u16x8  __attribute__((ext_vector_type(8)));

__device__ __attribute__((aligned(16))) uint16_t g_w1eff[CH * CH];
__device__ __attribute__((aligned(16))) float g_tap[5 * CH];   // tap-major
__device__ __attribute__((aligned(16))) float g_bias[CH];

static __device__ __forceinline__ uint16_t f32_to_bf16(float f) {
    uint32_t u = __builtin_bit_cast(uint32_t, f);
    u += 0x7FFFu + ((u >> 16) & 1u);
    return (uint16_t)(u >> 16);
}
static __device__ __forceinline__ float bf16_to_f32(uint16_t h) {
    uint32_t u = ((uint32_t)h) << 16;
    return __builtin_bit_cast(float, u);
}
// tanh-form gelu folded into exp2
static __device__ __forceinline__ float gelu_fast(float x) {
    const float A = 2.3022082f;
    const float B = 0.10294331f;
    float x2 = x * x;
    float z  = x * fmaf(x2, B, A);
    float e  = exp2f(z);
    float r  = __builtin_amdgcn_rcpf(1.0f + e);
    return fmaf(-x, r, x);
}

__global__ void prep_kernel(const float* __restrict__ w1, const float* __restrict__ b1,
                            const float* __restrict__ w3, const float* __restrict__ b3,
                            const float* __restrict__ w5, const float* __restrict__ b5,
                            const float* __restrict__ wc, const float* __restrict__ bc) {
    const int o = blockIdx.x;
    const int c = threadIdx.x;
    const float wc0 = wc[o * 3 + 0];
    g_w1eff[o * CH + c] = f32_to_bf16(wc0 * w1[o * CH + c]);
    if (c == 0) {
        const float wc1 = wc[o * 3 + 1], wc2 = wc[o * 3 + 2];
        g_tap[0 * CH + o] = wc2 * w5[o * 5 + 0];
        g_tap[1 * CH + o] = wc1 * w3[o * 3 + 0] + wc2 * w5[o * 5 + 1];
        g_tap[2 * CH + o] = wc1 * w3[o * 3 + 1] + wc2 * w5[o * 5 + 2];
        g_tap[3 * CH + o] = wc1 * w3[o * 3 + 2] + wc2 * w5[o * 5 + 3];
        g_tap[4 * CH + o] = wc2 * w5[o * 5 + 4];
        g_bias[o] = wc0 * b1[o] + wc1 * b3[o] + wc2 * b5[o] + bc[o];
    }
}

// k1: gelu + cast + transpose into aT[b][strip_row][c] bf16, where
// strip_row = 2 + t, element (t,c) stored at col c ^ ((t&7)<<3).
// Pad rows 0,1 (t=-2,-1) and 4098,4099 (t=4096,4097) zeroed with matching swizzle.
__global__ __launch_bounds__(256, 4)
void gelu_tr_kernel(const float* __restrict__ x, uint16_t* __restrict__ aT) {
    __shared__ __attribute__((aligned(16))) uint16_t sL[64 * 72];   // 9216 B

    const int tid = threadIdx.x;
    const int tb = blockIdx.x, cb = blockIdx.y, b = blockIdx.z;
    const int t0 = tb * 64, c0 = cb * 64;

    // read 64c x 64t f32 tile, gelu, stage to LDS [c][t]
    {
        const int cr = tid >> 2;       // 0..63 channel-local
        const int q  = tid & 3;        // 0..3 t-quarter (16 t)
        const float* xr = x + ((size_t)(b * CH + c0 + cr)) * TLEN + t0 + q * 16;
        f32x4 v0 = *(const f32x4*)(xr + 0);
        f32x4 v1 = *(const f32x4*)(xr + 4);
        f32x4 v2 = *(const f32x4*)(xr + 8);
        f32x4 v3 = *(const f32x4*)(xr + 12);
        u16x8 p0, p1;
#pragma unroll
        for (int j = 0; j < 4; ++j) {
            p0[j]     = f32_to_bf16(gelu_fast(v0[j]));
            p0[4 + j] = f32_to_bf16(gelu_fast(v1[j]));
            p1[j]     = f32_to_bf16(gelu_fast(v2[j]));
            p1[4 + j] = f32_to_bf16(gelu_fast(v3[j]));
        }
        *(u16x8*)(&sL[cr * 72 + q * 16 + 0]) = p0;
        *(u16x8*)(&sL[cr * 72 + q * 16 + 8]) = p1;
    }
    __syncthreads();

    // write transposed rows: chunk = (t-row tr, 8 channels)
    uint16_t* aTb = aT + (size_t)b * TPAD * CH;
#pragma unroll
    for (int i = 0; i < 2; ++i) {
        const int idx = tid + i * 256;
        const int tr  = idx >> 3;      // 0..63
        const int ch  = idx & 7;       // 0..7 c-chunk
        const int t   = t0 + tr;
        const int swz = (t & 7) << 3;
        u16x8 o;
#pragma unroll
        for (int j = 0; j < 8; ++j) o[j] = sL[(ch * 8 + j) * 72 + tr];
        *(u16x8*)(&aTb[(size_t)(2 + t) * CH + ((c0 + ch * 8) ^ swz)]) = o;
    }
    // zero pad rows (once per (b, cb), by tb==0 blocks)
    if (tb == 0) {
        const int pr = tid >> 6;       // 0..3
        const int cc = c0 + (tid & 63);
        const int prow = (pr < 2) ? pr : (4098 + (pr - 2));
        const int tmod = (pr < 2) ? (6 + pr) : (pr - 2);   // (t&7) of the pad row
        aTb[(size_t)prow * CH + (cc ^ (tmod << 3))] = 0;
    }
}

// k2: per (b, 64-t tile): linear 34 KB staging (9 loads in flight, then LDS
// writes), pipelined K-loop (weights from L2), in-register depthwise fold,
// then sA storage reused as wave-private transpose scratch (barrier-protected).
// sA row r <-> global t = t0 + r - 2; swizzle of row r = ((r+6)&7)<<3.
__global__ __launch_bounds__(256, 4)
void gemm_kernel(const uint16_t* __restrict__ aT, const float* __restrict__ x,
                 float* __restrict__ out) {
    __shared__ __attribute__((aligned(16))) uint16_t sA[68 * CH];      // 34816 B

    const int tid  = threadIdx.x;
    const int lane = tid & 63;
    const int wid  = tid >> 6;
    const int b    = blockIdx.y;
    const int t0   = blockIdx.x * TN;

    const float* __restrict__ xb = x + (size_t)b * CH * TLEN;
    float* __restrict__ ob = out + (size_t)b * CH * TLEN;

    // ---- staging: 2176 16B chunks; all loads issued before any LDS write ----
    {
        const u16x8* gsrc = (const u16x8*)(aT + (size_t)b * TPAD * CH + (size_t)t0 * CH);
        u16x8 stg[8], stgT;
#pragma unroll
        for (int i = 0; i < 8; ++i) stg[i] = gsrc[tid + i * 256];
        const bool tail = (tid < 128);
        if (tail) stgT = gsrc[tid + 2048];
        u16x8* ldst = (u16x8*)sA;
#pragma unroll
        for (int i = 0; i < 8; ++i) ldst[tid + i * 256] = stg[i];
        if (tail) ldst[tid + 2048] = stgT;
    }
    __syncthreads();   // B1

    f32x4 acc[4][4];
    const f32x4 vzero = {0.f, 0.f, 0.f, 0.f};
#pragma unroll
    for (int mi = 0; mi < 4; ++mi)
#pragma unroll
        for (int ni = 0; ni < 4; ++ni) acc[mi][ni] = vzero;

    const int m0   = wid * 64;
    const int colt = lane & 15;
    const int kgrp = (lane >> 4) * 8;

    // ---- K loop, 1-deep ping-pong; weights global (L2), a from sA ----
    const int swzB = (colt & 7) << 3;
    int rowB[4];
#pragma unroll
    for (int ni = 0; ni < 4; ++ni) rowB[ni] = (ni * 16 + colt + 2) * CH;

    bf16x8 afb[2][4], bfb[2][4];
#pragma unroll
    for (int mi = 0; mi < 4; ++mi) {
        const int co = m0 + mi * 16 + colt;
        afb[0][mi] = *(const bf16x8*)(g_w1eff + co * CH + kgrp);
    }
#pragma unroll
    for (int ni = 0; ni < 4; ++ni)
        bfb[0][ni] = *(const bf16x8*)(&sA[rowB[ni] + (kgrp ^ swzB)]);
#pragma unroll
    for (int s = 0; s < 8; ++s) {
        const int cur = s & 1, nxt = cur ^ 1;
        if (s < 7) {
            const int kk = (s + 1) * 32;
#pragma unroll
            for (int mi = 0; mi < 4; ++mi) {
                const int co = m0 + mi * 16 + colt;
                afb[nxt][mi] = *(const bf16x8*)(g_w1eff + co * CH + kk + kgrp);
            }
            const int cin = kk + kgrp;
#pragma unroll
            for (int ni = 0; ni < 4; ++ni)
                bfb[nxt][ni] = *(const bf16x8*)(&sA[rowB[ni] + (cin ^ swzB)]);
        }
#pragma unroll
        for (int mi = 0; mi < 4; ++mi)
#pragma unroll
            for (int ni = 0; ni < 4; ++ni)
                acc[mi][ni] = __builtin_amdgcn_mfma_f32_16x16x32_bf16(afb[cur][mi], bfb[cur][ni], acc[mi][ni], 0, 0, 0);
    }

    // ---- phase A: depthwise + bias folded into acc ----
    const int rg = (lane >> 4) * 4;
    int swzA[5];
#pragma unroll
    for (int k = 0; k < 5; ++k) swzA[k] = ((colt + k + 6) & 7) << 3;
#pragma unroll
    for (int mi = 0; mi < 4; ++mi) {
        const int c = m0 + mi * 16 + rg;
        const f32x4 tp0 = *(const f32x4*)(g_tap + 0 * CH + c);
        const f32x4 tp1 = *(const f32x4*)(g_tap + 1 * CH + c);
        const f32x4 tp2 = *(const f32x4*)(g_tap + 2 * CH + c);
        const f32x4 tp3 = *(const f32x4*)(g_tap + 3 * CH + c);
        const f32x4 tp4 = *(const f32x4*)(g_tap + 4 * CH + c);
        const f32x4 bsv = *(const f32x4*)(g_bias + c);
#pragma unroll
        for (int ni = 0; ni < 4; ++ni) {
            const int t = ni * 16 + colt;
            u16x4 a0 = *(const u16x4*)(&sA[(t + 0) * CH + (c ^ swzA[0])]);
            u16x4 a1 = *(const u16x4*)(&sA[(t + 1) * CH + (c ^ swzA[1])]);
            u16x4 a2 = *(const u16x4*)(&sA[(t + 2) * CH + (c ^ swzA[2])]);
            u16x4 a3 = *(const u16x4*)(&sA[(t + 3) * CH + (c ^ swzA[3])]);
            u16x4 a4 = *(const u16x4*)(&sA[(t + 4) * CH + (c ^ swzA[4])]);
#pragma unroll
            for (int r = 0; r < 4; ++r) {
                float d = tp0[r] * bf16_to_f32(a0[r]);
                d = fmaf(tp1[r], bf16_to_f32(a1[r]), d);
                d = fmaf(tp2[r], bf16_to_f32(a2[r]), d);
                d = fmaf(tp3[r], bf16_to_f32(a3[r]), d);
                d = fmaf(tp4[r], bf16_to_f32(a4[r]), d);
                acc[mi][ni][r] += d + bsv[r];
            }
        }
    }
    __syncthreads();   // B2: all sA reads done; sA becomes f32 scratch

    // ---- phase B: wave-private transpose through sA storage; residual from x
    //      (L3-hot), x loads pipelined one mi ahead ----
    float* __restrict__ sw = ((float*)sA) + wid * (16 * SST);   // 4352 B/wave
    const int ci = lane >> 2;          // 0..15 channel-local
    const int q  = lane & 3;           // 0..3 -> 16 t each

    f32x4 xv[2][4];
    {
        const int cc = m0 + ci;
        const float* xrow = xb + (size_t)cc * TLEN + t0 + q * 16;
        xv[0][0] = *(const f32x4*)(xrow + 0);
        xv[0][1] = *(const f32x4*)(xrow + 4);
        xv[0][2] = *(const f32x4*)(xrow + 8);
        xv[0][3] = *(const f32x4*)(xrow + 12);
    }
#pragma unroll
    for (int mi = 0; mi < 4; ++mi) {
        const int cur = mi & 1, nxt = cur ^ 1;
        if (mi < 3) {
            const int cc = m0 + (mi + 1) * 16 + ci;
            const float* xrow = xb + (size_t)cc * TLEN + t0 + q * 16;
            xv[nxt][0] = *(const f32x4*)(xrow + 0);
            xv[nxt][1] = *(const f32x4*)(xrow + 4);
            xv[nxt][2] = *(const f32x4*)(xrow + 8);
            xv[nxt][3] = *(const f32x4*)(xrow + 12);
        }
#pragma unroll
        for (int ni = 0; ni < 4; ++ni) {
            const int t = ni * 16 + colt;
#pragma unroll
            for (int r = 0; r < 4; ++r) sw[(rg + r) * SST + t] = acc[mi][ni][r];
        }
        const int cc = m0 + mi * 16 + ci;
        float* orow = ob + (size_t)cc * TLEN + t0 + q * 16;
        const float* srow = sw + ci * SST + q * 16;
        f32x4 s0 = *(const f32x4*)(srow + 0);
        f32x4 s1 = *(const f32x4*)(srow + 4);
        f32x4 s2 = *(const f32x4*)(srow + 8);
        f32x4 s3 = *(const f32x4*)(srow + 12);
        *(f32x4*)(orow + 0)  = s0 + xv[cur][0];
        *(f32x4*)(orow + 4)  = s1 + xv[cur][1];
        *(f32x4*)(orow + 8)  = s2 + xv[cur][2];
        *(f32x4*)(orow + 12) = s3 + xv[cur][3];
    }
}

extern "C" void kernel_launch(void* const* d_in, const int* in_sizes, int n_in,
                              void* d_out, int out_size, void* d_ws, size_t ws_size,
                              hipStream_t stream) {
    const float* x  = (const float*)d_in[0];
    const float* w1 = (const float*)d_in[1];
    const float* b1 = (const float*)d_in[2];
    const float* w3 = (const float*)d_in[3];
    const float* b3 = (const float*)d_in[4];
    const float* w5 = (const float*)d_in[5];
    const float* b5 = (const float*)d_in[6];
    const float* wc = (const float*)d_in[7];
    const float* bc = (const float*)d_in[8];
    float* out = (float*)d_out;
    uint16_t* aT = (uint16_t*)d_ws;    // 32*4100*256*2 B = 67.2 MB

    prep_kernel<<<dim3(CH), dim3(CH), 0, stream>>>(w1, b1, w3, b3, w5, b5, wc, bc);
    gelu_tr_kernel<<<dim3(TLEN / 64, CH / 64, BATCH), dim3(256), 0, stream>>>(x, aT);
    gemm_kernel<<<dim3(TLEN / TN, BATCH), dim3(256), 0, stream>>>(aT, x, out);
}

// Round 15
// 142.483 us; speedup vs baseline: 1.9284x; 1.9284x over previous
//
#include <hip/hip_runtime.h>
#include <stdint.h>

#define BATCH 32
#define CH    256
#define TLEN  4096
#define TN    64
#define NT    4             // tiles per block -> block covers 256 t
#define TPAD  4100          // aT rows per batch strip: 2 pad + 4096 + 2 pad
#define SST   68            // phase-B f32 scratch row stride

typedef short    bf16x8 __attribute__((ext_vector_type(8)));
typedef float    f32x4  __attribute__((ext_vector_type(4)));
typedef uint16_t u16x4  __attribute__((ext_vector_type(4)));
typedef uint16_t u16x8  __attribute__((ext_vector_type(8)));

typedef const uint32_t __attribute__((address_space(1))) as1_u32;
typedef uint32_t       __attribute__((address_space(3))) as3_u32;

__device__ __attribute__((aligned(16))) uint16_t g_w1eff[CH * CH];
__device__ __attribute__((aligned(16))) float g_tap[5 * CH];   // tap-major
__device__ __attribute__((aligned(16))) float g_bias[CH];

static __device__ __forceinline__ uint16_t f32_to_bf16(float f) {
    uint32_t u = __builtin_bit_cast(uint32_t, f);
    u += 0x7FFFu + ((u >> 16) & 1u);
    return (uint16_t)(u >> 16);
}
static __device__ __forceinline__ float bf16_to_f32(uint16_t h) {
    uint32_t u = ((uint32_t)h) << 16;
    return __builtin_bit_cast(float, u);
}
// tanh-form gelu folded into exp2
static __device__ __forceinline__ float gelu_fast(float x) {
    const float A = 2.3022082f;
    const float B = 0.10294331f;
    float x2 = x * x;
    float z  = x * fmaf(x2, B, A);
    float e  = exp2f(z);
    float r  = __builtin_amdgcn_rcpf(1.0f + e);
    return fmaf(-x, r, x);
}

__global__ void prep_kernel(const float* __restrict__ w1, const float* __restrict__ b1,
                            const float* __restrict__ w3, const float* __restrict__ b3,
                            const float* __restrict__ w5, const float* __restrict__ b5,
                            const float* __restrict__ wc, const float* __restrict__ bc) {
    const int o = blockIdx.x;
    const int c = threadIdx.x;
    const float wc0 = wc[o * 3 + 0];
    g_w1eff[o * CH + c] = f32_to_bf16(wc0 * w1[o * CH + c]);
    if (c == 0) {
        const float wc1 = wc[o * 3 + 1], wc2 = wc[o * 3 + 2];
        g_tap[0 * CH + o] = wc2 * w5[o * 5 + 0];
        g_tap[1 * CH + o] = wc1 * w3[o * 3 + 0] + wc2 * w5[o * 5 + 1];
        g_tap[2 * CH + o] = wc1 * w3[o * 3 + 1] + wc2 * w5[o * 5 + 2];
        g_tap[3 * CH + o] = wc1 * w3[o * 3 + 2] + wc2 * w5[o * 5 + 3];
        g_tap[4 * CH + o] = wc2 * w5[o * 5 + 4];
        g_bias[o] = wc0 * b1[o] + wc1 * b3[o] + wc2 * b5[o] + bc[o];
    }
}

// k1: gelu + cast + transpose into aT[b][strip_row][c] bf16, where
// strip_row = 2 + t, element (t,c) stored at col c ^ ((t&7)<<3).
// Pad rows 0,1 (t=-2,-1) and 4098,4099 (t=4096,4097) zeroed with matching swizzle.
__global__ __launch_bounds__(256, 4)
void gelu_tr_kernel(const float* __restrict__ x, uint16_t* __restrict__ aT) {
    __shared__ __attribute__((aligned(16))) uint16_t sL[64 * 72];   // 9216 B

    const int tid = threadIdx.x;
    const int tb = blockIdx.x, cb = blockIdx.y, b = blockIdx.z;
    const int t0 = tb * 64, c0 = cb * 64;

    {
        const int cr = tid >> 2;       // 0..63 channel-local
        const int q  = tid & 3;        // 0..3 t-quarter (16 t)
        const float* xr = x + ((size_t)(b * CH + c0 + cr)) * TLEN + t0 + q * 16;
        f32x4 v0 = *(const f32x4*)(xr + 0);
        f32x4 v1 = *(const f32x4*)(xr + 4);
        f32x4 v2 = *(const f32x4*)(xr + 8);
        f32x4 v3 = *(const f32x4*)(xr + 12);
        u16x8 p0, p1;
#pragma unroll
        for (int j = 0; j < 4; ++j) {
            p0[j]     = f32_to_bf16(gelu_fast(v0[j]));
            p0[4 + j] = f32_to_bf16(gelu_fast(v1[j]));
            p1[j]     = f32_to_bf16(gelu_fast(v2[j]));
            p1[4 + j] = f32_to_bf16(gelu_fast(v3[j]));
        }
        *(u16x8*)(&sL[cr * 72 + q * 16 + 0]) = p0;
        *(u16x8*)(&sL[cr * 72 + q * 16 + 8]) = p1;
    }
    __syncthreads();

    uint16_t* aTb = aT + (size_t)b * TPAD * CH;
#pragma unroll
    for (int i = 0; i < 2; ++i) {
        const int idx = tid + i * 256;
        const int tr  = idx >> 3;      // 0..63
        const int ch  = idx & 7;       // 0..7 c-chunk
        const int t   = t0 + tr;
        const int swz = (t & 7) << 3;
        u16x8 o;
#pragma unroll
        for (int j = 0; j < 8; ++j) o[j] = sL[(ch * 8 + j) * 72 + tr];
        *(u16x8*)(&aTb[(size_t)(2 + t) * CH + ((c0 + ch * 8) ^ swz)]) = o;
    }
    if (tb == 0) {
        const int pr = tid >> 6;       // 0..3
        const int cc = c0 + (tid & 63);
        const int prow = (pr < 2) ? pr : (4098 + (pr - 2));
        const int tmod = (pr < 2) ? (6 + pr) : (pr - 2);   // (t&7) of the pad row
        aTb[(size_t)prow * CH + (cc ^ (tmod << 3))] = 0;
    }
}

// k2: block = (batch b, 256-t strip) = 4 tiles of 64 t. Double-buffered sA;
// tile i+1 staged via global_load_lds (width 16, linear: swizzle pre-baked by k1)
// while tile i runs K-loop + epilogue. Phase-B scratch reuses the retired buffer.
// Buffer row r <-> tile-local t = r - 2; swizzle of row r = ((r+6)&7)<<3.
__global__ __launch_bounds__(256, 2)
void gemm_kernel(const uint16_t* __restrict__ aT, const float* __restrict__ x,
                 float* __restrict__ out) {
    __shared__ __attribute__((aligned(16))) uint16_t sA[2][68 * CH];   // 69632 B

    const int tid  = threadIdx.x;
    const int lane = tid & 63;
    const int wid  = tid >> 6;
    const int b    = blockIdx.y;
    const int t0b  = blockIdx.x * (TN * NT);

    const float* __restrict__ xb = x + (size_t)b * CH * TLEN;
    float* __restrict__ ob = out + (size_t)b * CH * TLEN;
    const uint16_t* __restrict__ aTb = aT + (size_t)b * TPAD * CH;

    const int m0   = wid * 64;
    const int colt = lane & 15;
    const int kgrp = (lane >> 4) * 8;
    const int rg   = (lane >> 4) * 4;
    const int ci   = lane >> 2;        // 0..15 channel-local (phase B)
    const int q    = lane & 3;         // 0..3 -> 16 t each   (phase B)

    // ---- prologue: stage tile 0 into buf 0 (34 x 1KB wave-ops) ----
    {
        const uint16_t* gsrc = aTb + (size_t)t0b * CH;
        for (int j = wid; j < 34; j += 4) {
            const uint16_t* gp = gsrc + j * 512 + lane * 8;
            uint16_t* lp = &sA[0][j * 512];
            __builtin_amdgcn_global_load_lds((as1_u32*)gp, (as3_u32*)lp, 16, 0, 0);
        }
    }

    const int swzB = (colt & 7) << 3;
    int rowB[4];
#pragma unroll
    for (int ni = 0; ni < 4; ++ni) rowB[ni] = (ni * 16 + colt + 2) * CH;
    int swzA[5];
#pragma unroll
    for (int k = 0; k < 5; ++k) swzA[k] = ((colt + k + 6) & 7) << 3;

    for (int i = 0; i < NT; ++i) {
        const int cur = i & 1;
        __syncthreads();   // B1: buf[cur] staged (vmcnt drained); prev scratch done

        // ---- prefetch tile i+1 into buf[cur^1] (overlaps K-loop + phase A) ----
        if (i + 1 < NT) {
            const uint16_t* gsrc = aTb + (size_t)(t0b + (i + 1) * TN) * CH;
            for (int j = wid; j < 34; j += 4) {
                const uint16_t* gp = gsrc + j * 512 + lane * 8;
                uint16_t* lp = &sA[cur ^ 1][j * 512];
                __builtin_amdgcn_global_load_lds((as1_u32*)gp, (as3_u32*)lp, 16, 0, 0);
            }
        }

        const uint16_t* sAc = sA[cur];
        const int t0 = t0b + i * TN;

        f32x4 acc[4][4];
        const f32x4 vzero = {0.f, 0.f, 0.f, 0.f};
#pragma unroll
        for (int mi = 0; mi < 4; ++mi)
#pragma unroll
            for (int ni = 0; ni < 4; ++ni) acc[mi][ni] = vzero;

        // ---- K loop, 1-deep ping-pong; weights global (L2), a from sAc ----
        bf16x8 afb[2][4], bfb[2][4];
#pragma unroll
        for (int mi = 0; mi < 4; ++mi) {
            const int co = m0 + mi * 16 + colt;
            afb[0][mi] = *(const bf16x8*)(g_w1eff + co * CH + kgrp);
        }
#pragma unroll
        for (int ni = 0; ni < 4; ++ni)
            bfb[0][ni] = *(const bf16x8*)(&sAc[rowB[ni] + (kgrp ^ swzB)]);
#pragma unroll
        for (int s = 0; s < 8; ++s) {
            const int c2 = s & 1, nx = c2 ^ 1;
            if (s < 7) {
                const int kk = (s + 1) * 32;
#pragma unroll
                for (int mi = 0; mi < 4; ++mi) {
                    const int co = m0 + mi * 16 + colt;
                    afb[nx][mi] = *(const bf16x8*)(g_w1eff + co * CH + kk + kgrp);
                }
                const int cin = kk + kgrp;
#pragma unroll
                for (int ni = 0; ni < 4; ++ni)
                    bfb[nx][ni] = *(const bf16x8*)(&sAc[rowB[ni] + (cin ^ swzB)]);
            }
#pragma unroll
            for (int mi = 0; mi < 4; ++mi)
#pragma unroll
                for (int ni = 0; ni < 4; ++ni)
                    acc[mi][ni] = __builtin_amdgcn_mfma_f32_16x16x32_bf16(afb[c2][mi], bfb[c2][ni], acc[mi][ni], 0, 0, 0);
        }

        // ---- phase A: depthwise + bias folded into acc ----
#pragma unroll
        for (int mi = 0; mi < 4; ++mi) {
            const int c = m0 + mi * 16 + rg;
            const f32x4 tp0 = *(const f32x4*)(g_tap + 0 * CH + c);
            const f32x4 tp1 = *(const f32x4*)(g_tap + 1 * CH + c);
            const f32x4 tp2 = *(const f32x4*)(g_tap + 2 * CH + c);
            const f32x4 tp3 = *(const f32x4*)(g_tap + 3 * CH + c);
            const f32x4 tp4 = *(const f32x4*)(g_tap + 4 * CH + c);
            const f32x4 bsv = *(const f32x4*)(g_bias + c);
#pragma unroll
            for (int ni = 0; ni < 4; ++ni) {
                const int t = ni * 16 + colt;
                u16x4 a0 = *(const u16x4*)(&sAc[(t + 0) * CH + (c ^ swzA[0])]);
                u16x4 a1 = *(const u16x4*)(&sAc[(t + 1) * CH + (c ^ swzA[1])]);
                u16x4 a2 = *(const u16x4*)(&sAc[(t + 2) * CH + (c ^ swzA[2])]);
                u16x4 a3 = *(const u16x4*)(&sAc[(t + 3) * CH + (c ^ swzA[3])]);
                u16x4 a4 = *(const u16x4*)(&sAc[(t + 4) * CH + (c ^ swzA[4])]);
#pragma unroll
                for (int r = 0; r < 4; ++r) {
                    float d = tp0[r] * bf16_to_f32(a0[r]);
                    d = fmaf(tp1[r], bf16_to_f32(a1[r]), d);
                    d = fmaf(tp2[r], bf16_to_f32(a2[r]), d);
                    d = fmaf(tp3[r], bf16_to_f32(a3[r]), d);
                    d = fmaf(tp4[r], bf16_to_f32(a4[r]), d);
                    acc[mi][ni][r] += d + bsv[r];
                }
            }
        }
        __syncthreads();   // B2: all reads of buf[cur] done; it becomes f32 scratch

        // ---- phase B: wave-private transpose in retired buffer; residual from x ----
        float* __restrict__ sw = ((float*)sA[cur]) + wid * (16 * SST);   // 4352 B/wave
#pragma unroll
        for (int mi = 0; mi < 4; ++mi) {
            const int cc = m0 + mi * 16 + ci;
            const float* xrow = xb + (size_t)cc * TLEN + t0 + q * 16;
            f32x4 xv0 = *(const f32x4*)(xrow + 0);
            f32x4 xv1 = *(const f32x4*)(xrow + 4);
            f32x4 xv2 = *(const f32x4*)(xrow + 8);
            f32x4 xv3 = *(const f32x4*)(xrow + 12);
#pragma unroll
            for (int ni = 0; ni < 4; ++ni) {
                const int t = ni * 16 + colt;
#pragma unroll
                for (int r = 0; r < 4; ++r) sw[(rg + r) * SST + t] = acc[mi][ni][r];
            }
            float* orow = ob + (size_t)cc * TLEN + t0 + q * 16;
            const float* srow = sw + ci * SST + q * 16;
            f32x4 s0 = *(const f32x4*)(srow + 0);
            f32x4 s1 = *(const f32x4*)(srow + 4);
            f32x4 s2 = *(const f32x4*)(srow + 8);
            f32x4 s3 = *(const f32x4*)(srow + 12);
            *(f32x4*)(orow + 0)  = s0 + xv0;
            *(f32x4*)(orow + 4)  = s1 + xv1;
            *(f32x4*)(orow + 8)  = s2 + xv2;
            *(f32x4*)(orow + 12) = s3 + xv3;
        }
    }
}

extern "C" void kernel_launch(void* const* d_in, const int* in_sizes, int n_in,
                              void* d_out, int out_size, void* d_ws, size_t ws_size,
                              hipStream_t stream) {
    const float* x  = (const float*)d_in[0];
    const float* w1 = (const float*)d_in[1];
    const float* b1 = (const float*)d_in[2];
    const float* w3 = (const float*)d_in[3];
    const float* b3 = (const float*)d_in[4];
    const float* w5 = (const float*)d_in[5];
    const float* b5 = (const float*)d_in[6];
    const float* wc = (const float*)d_in[7];
    const float* bc = (const float*)d_in[8];
    float* out = (float*)d_out;
    uint16_t* aT = (uint16_t*)d_ws;    // 32*4100*256*2 B = 67.2 MB

    prep_kernel<<<dim3(CH), dim3(CH), 0, stream>>>(w1, b1, w3, b3, w5, b5, wc, bc);
    gelu_tr_kernel<<<dim3(TLEN / 64, CH / 64, BATCH), dim3(256), 0, stream>>>(x, aT);
    gemm_kernel<<<dim3(TLEN / (TN * NT), BATCH), dim3(256), 0, stream>>>(aT, x, out);
}